// Round 5
// baseline (230.530 us; speedup 1.0000x reference)
//
#include <hip/hip_runtime.h>
#include <stdint.h>

typedef int v4i __attribute__((ext_vector_type(4)));

// Problem constants (from reference)
constexpr int G = 7, B = 8, M = 512, N = 512, K = 1024;
constexpr int GBn = G * B;                       // 56
// X_ZP = -66, Y_ZP = 160 (hardcoded in reference)
// With y' = y - 128:  sum (x-X)(y-Y) = dot(x,y') - 32*rowsum_x + 66*colsum_y' - 2162688

// ws layout: yt [b][n][k] int8 (y-128), then csp[16][B*N] per-k-tile colsum partials
constexpr size_t YT_BYTES = (size_t)B * N * K;   // 4,194,304
constexpr size_t CSP_CNT  = (size_t)16 * B * N;  // 65,536 ints
constexpr size_t WS_NEEDED = YT_BYTES + CSP_CNT * 4;

// ---------------------------------------------------------------------------
// K1: transpose + pack y:  y[b][k][n] (int32, 0..255)  ->  yt[b][n][k] (int8, y-128)
// plus per-(k-tile, b, n) partial colsums of y' into csp.
// 64x64 tiles through LDS. Grid: (N/64, K/64, B), block 256.
// ---------------------------------------------------------------------------
__global__ __launch_bounds__(256) void transpose_pack_y(const int* __restrict__ y,
                                                        signed char* __restrict__ yt,
                                                        int* __restrict__ csp) {
    __shared__ unsigned char tile[64][80];       // 80 = 5*16: 16B-aligned rows, odd 16-bank phase
    int n0  = blockIdx.x * 64;
    int k0t = blockIdx.y;
    int k0  = k0t * 64;
    int b   = blockIdx.z;
    int t   = threadIdx.x;

    // phase 1: coalesced read along n, pack low bytes (^0x80 == y-128 as i8), 16B to LDS
    int r  = t >> 2;                              // k-local 0..63
    int c0 = (t & 3) * 16;                        // n-local byte offset
    const int* src = y + ((size_t)b * K + k0 + r) * N + n0 + c0;
    uint32_t p[4];
#pragma unroll
    for (int q = 0; q < 4; ++q) {
        int4 v = ((const int4*)src)[q];
        p[q] =  (uint32_t)((v.x & 255) ^ 128)
             | ((uint32_t)((v.y & 255) ^ 128) << 8)
             | ((uint32_t)((v.z & 255) ^ 128) << 16)
             | ((uint32_t)((v.w & 255) ^ 128) << 24);
    }
    *(uint4*)&tile[r][c0] = make_uint4(p[0], p[1], p[2], p[3]);
    __syncthreads();

    // phase 2: gather a column of 16 k-bytes per thread, write 16B contiguous in k
    int nl = t >> 2;                              // n-local 0..63
    int kc = (t & 3) * 16;                        // k-local byte offset
    uint32_t q[4];
    int s = 0;
#pragma unroll
    for (int w = 0; w < 4; ++w) {
        uint32_t b0 = tile[kc + w * 4 + 0][nl];
        uint32_t b1 = tile[kc + w * 4 + 1][nl];
        uint32_t b2 = tile[kc + w * 4 + 2][nl];
        uint32_t b3 = tile[kc + w * 4 + 3][nl];
        s += (int)(signed char)b0 + (int)(signed char)b1
           + (int)(signed char)b2 + (int)(signed char)b3;
        q[w] = b0 | (b1 << 8) | (b2 << 16) | (b3 << 24);
    }
    *(uint4*)(yt + ((size_t)b * N + n0 + nl) * K + k0 + kc) = make_uint4(q[0], q[1], q[2], q[3]);

    // quad-reduce partial colsum (4 threads cover 64 k for one n)
    s += __shfl_xor(s, 1, 64);
    s += __shfl_xor(s, 2, 64);
    if ((t & 3) == 0) csp[(size_t)k0t * (B * N) + b * N + n0 + nl] = s;
}

// ---------------------------------------------------------------------------
// K2 (fused GEMM), round-5 restructure: A-panel-resident, barrier-free K-loop.
//
// Round 1-3 post-mortem: per-step __syncthreads drains vmcnt(0), serializing
// (64KB load burst) -> (wait last byte) -> (0.55us MFMA) x16, chip-wide in
// lockstep; the per-step x reads are 256B @ 4KB stride (DRAM page thrash).
// Effective staging BW ~2 TB/s regardless of occupancy. Fix: remove per-step
// HBM dependency AND per-step barriers entirely.
//
// Block = 128m x 512n (full N) for one (gb, mt). 1024 threads, 16 waves
// (2m x 8n), each wave 64x64 via 4x4 mfma_i32_16x16x64_i8.
//   PROLOGUE: block reads its CONTIGUOUS 512KB x panel (streamed, page-local,
//     ~500 loads/thread-group in flight), packs int32->int8 into a 128KB
//     swizzled LDS panel, accumulates rowsums. ONE __syncthreads.
//   K-LOOP (no barriers, full unroll): af from LDS panel (immediate offsets),
//     bf per-lane 16B direct from yt (L2-resident; offsets fold to imm).
//     Waves drift freely; L2 latency hidden by 4 waves/SIMD TLP vs MFMA issue.
//   EPILOGUE: zero-point correction + scale, coalesced stores.
//
// LDS panel swizzle (full-K rows): 16B chunk c of row r stored at c ^ (r&7).
//   write: 2-way bank alias (free). read af: 16 fr-rows -> 8 slots x 2 = 2-way.
// LDS: 128KB panel + 2KB cs + 0.5KB rs = 130.5KB -> 1 block/CU, 16 waves.
// Grid: 224 = 56 gb x 4 mt, XCD-bijective swizzle (each XCD's 7 gb -> 7 b-
// slices of yt = 3.5MB < 4MB XCD L2).
// ---------------------------------------------------------------------------
__global__ __launch_bounds__(1024) void gemm_fused(const int* __restrict__ x,
                                                   const signed char* __restrict__ yt,
                                                   const int* __restrict__ csp,
                                                   const float* __restrict__ xsp,
                                                   const float* __restrict__ ysp,
                                                   float* __restrict__ out) {
    __shared__ __align__(16) signed char Ap[128 * 1024];   // 128 KiB packed panel
    __shared__ int cs_lds[512];
    __shared__ int rs_lds[128];

    int id  = blockIdx.x;                         // 0..223
    int swz = (id & 7) * 28 + (id >> 3);          // XCD-contiguous chunks (224%8==0, bijective)
    int gb  = swz >> 2;                           // 0..55
    int mt  = swz & 3;                            // 0..3
    int b   = gb & 7;

    int tid = threadIdx.x, wave = tid >> 6, lane = tid & 63;

    // block colsums: first 512 threads each sum 16 per-k-tile partials for one n
    if (tid < 512) {
        int s = 0;
        const int* p = csp + b * N + tid;
#pragma unroll
        for (int kt = 0; kt < 16; ++kt) s += p[(size_t)kt * (B * N)];
        cs_lds[tid] = s;
    }

    // ---- prologue: stream the 512KB x panel, pack to LDS, rowsums ----
    // thread t: row r = t>>3 (8 threads/row), int4 columns a8 + 8i, i=0..31
    // (per-instruction: 8 x 128B coalesced segments per wave; per-row the 8
    //  threads interleave -> full sequential coverage, page-local)
    int r  = tid >> 3;
    int a8 = tid & 7;
    const int4* Arow = (const int4*)(x + ((size_t)(gb * M + mt * 128 + r)) * K);
    int rsum = 0;
#pragma unroll
    for (int ii = 0; ii < 4; ++ii) {
        int4 v[8];
#pragma unroll
        for (int u = 0; u < 8; ++u) v[u] = Arow[a8 + 8 * (ii * 8 + u)];
#pragma unroll
        for (int u = 0; u < 8; ++u) {
            int i = ii * 8 + u;
            int4 t = v[u];
            rsum += t.x + t.y + t.z + t.w;
            uint32_t w =  (uint32_t)(t.x & 255)
                       | ((uint32_t)(t.y & 255) << 8)
                       | ((uint32_t)(t.z & 255) << 16)
                       | ((uint32_t)(t.w & 255) << 24);
            int c = (a8 >> 2) + 2 * i;            // logical 16B chunk (0..63)
            *(uint32_t*)(&Ap[r * 1024 + ((c ^ (r & 7)) << 4) + ((a8 & 3) << 2)]) = w;
        }
    }
    rsum += __shfl_xor(rsum, 1, 64);
    rsum += __shfl_xor(rsum, 2, 64);
    rsum += __shfl_xor(rsum, 4, 64);
    if ((tid & 7) == 0) rs_lds[r] = rsum;

    __syncthreads();   // the ONLY barrier: panel + rs + cs ready

    // ---- K-loop: barrier-free ----
    int fr = lane & 15;                           // row-in-tile (A) / col-in-tile (B)
    int h  = lane >> 4;                           // k-chunk selector (0..3)
    int s3 = fr & 7;
    int wm = (wave >> 3) * 64;                    // 0 or 64
    int wn = (wave & 7) * 64;                     // 0,64,...,448

    // A fragment bases: addr(t,i) = base(t&1) + (t>>1)*128 + i*16384
    //   chunk(t) = (t*4+h) ^ s3 ; (t*4+h) = (t>>1)*8 + (t&1)*4 + h
    int arow0 = (wm + fr) * 1024;
    int aeven = arow0 + (((h)      ^ s3) << 4);
    int aodd  = arow0 + (((4 + h)  ^ s3) << 4);

    // B fragment base: lane reads 16B of row (wn + j*16 + fr) at k = t*64+h*16
    const signed char* Bj0 = yt + ((size_t)(b * N + wn + fr)) * K + h * 16;

    v4i zero = {0, 0, 0, 0};
    v4i acc[4][4];
#pragma unroll
    for (int i = 0; i < 4; ++i)
#pragma unroll
        for (int j = 0; j < 4; ++j) acc[i][j] = zero;

#pragma unroll
    for (int t = 0; t < 16; ++t) {
        v4i bf[4], af[4];
#pragma unroll
        for (int j = 0; j < 4; ++j)
            bf[j] = *(const v4i*)(Bj0 + (size_t)j * 16 * K + t * 64);
        int ab = (t & 1) ? aodd : aeven;
#pragma unroll
        for (int i = 0; i < 4; ++i)
            af[i] = *(const v4i*)(&Ap[ab + i * 16384 + (t >> 1) * 128]);
#pragma unroll
        for (int i = 0; i < 4; ++i)
#pragma unroll
            for (int j = 0; j < 4; ++j)
                acc[i][j] = __builtin_amdgcn_mfma_i32_16x16x64_i8(af[i], bf[j], acc[i][j], 0, 0, 0);
    }

    // ---- epilogue: C = s * (dot - 32*rowsum_x + 66*colsum_y' - 2162688) ----
    float sc = xsp[0] * ysp[0];
    int colL = lane & 15;
    int rowQ = (lane >> 4) * 4;
    float* outg = out + (size_t)gb * (M * N) + (size_t)(mt * 128) * N;
#pragma unroll
    for (int i = 0; i < 4; ++i) {
#pragma unroll
        for (int rr = 0; rr < 4; ++rr) {
            int row_l = wm + i * 16 + rowQ + rr;
            int rsv = rs_lds[row_l];
#pragma unroll
            for (int j = 0; j < 4; ++j) {
                int col = wn + j * 16 + colL;
                int tv = acc[i][j][rr] - 32 * rsv + 66 * cs_lds[col] - 2162688;
                outg[(size_t)row_l * N + col] = sc * (float)tv;
            }
        }
    }
}

// ---------------------------------------------------------------------------
// Fallback (only if ws_size is too small): naive but correct.
// sum (x-X)(y-Y) = dot(x,y) - 160*sum_x + 66*sum_y - 10,813,440
// ---------------------------------------------------------------------------
__global__ __launch_bounds__(256) void naive_kernel(const int* __restrict__ x,
                                                    const int* __restrict__ y,
                                                    const float* __restrict__ xsp,
                                                    const float* __restrict__ ysp,
                                                    float* __restrict__ out) {
    size_t idx = (size_t)blockIdx.x * 256 + threadIdx.x;   // over 14,680,064
    int n  = (int)(idx & 511);
    int m  = (int)((idx >> 9) & 511);
    int gb = (int)(idx >> 18);
    int b  = gb & 7;
    const int* xr = x + ((size_t)gb * M + m) * K;
    const int* yc = y + (size_t)b * K * N + n;
    int dot = 0, sx = 0, sy = 0;
    for (int k = 0; k < K; ++k) {
        int a = xr[k];
        int c = yc[(size_t)k * N];
        dot += a * c; sx += a; sy += c;
    }
    float s = xsp[0] * ysp[0];
    out[idx] = s * (float)(dot - 160 * sx + 66 * sy - 10813440);
}

// ---------------------------------------------------------------------------
extern "C" void kernel_launch(void* const* d_in, const int* in_sizes, int n_in,
                              void* d_out, int out_size, void* d_ws, size_t ws_size,
                              hipStream_t stream) {
    const int*   x  = (const int*)d_in[0];     // [7,8,512,1024] int8 values in int32
    const int*   y  = (const int*)d_in[1];     // [8,1024,512] uint8 values in int32
    const float* xs = (const float*)d_in[2];
    const float* ys = (const float*)d_in[3];
    float* out = (float*)d_out;

    if (ws_size < WS_NEEDED) {
        naive_kernel<<<(14680064 + 255) / 256, 256, 0, stream>>>(x, y, xs, ys, out);
        return;
    }

    char* ws = (char*)d_ws;
    signed char* yt  = (signed char*)ws;
    int*         csp = (int*)(ws + YT_BYTES);

    transpose_pack_y<<<dim3(N / 64, K / 64, B), 256, 0, stream>>>(y, yt, csp);
    gemm_fused<<<dim3(224), 1024, 0, stream>>>(x, yt, csp, xs, ys, out);
}

// Round 6
// 216.685 us; speedup vs baseline: 1.0639x; 1.0639x over previous
//
#include <hip/hip_runtime.h>
#include <stdint.h>

#define AS1 __attribute__((address_space(1)))
#define AS3 __attribute__((address_space(3)))

typedef int v4i __attribute__((ext_vector_type(4)));

// Problem constants (from reference)
constexpr int G = 7, B = 8, M = 512, N = 512, K = 1024;
constexpr int GBn = G * B;                       // 56
// X_ZP = -66, Y_ZP = 160 (hardcoded in reference)
// With y' = y - 128:  sum (x-X)(y-Y) = dot(x,y') - 32*rowsum_x + 66*colsum_y' - 2162688

// ws layout: yt [b][n][k] int8 (y-128), then csp[16][B*N] per-k-tile colsum partials
constexpr size_t YT_BYTES = (size_t)B * N * K;   // 4,194,304
constexpr size_t CSP_CNT  = (size_t)16 * B * N;  // 65,536 ints
constexpr size_t WS_NEEDED = YT_BYTES + CSP_CNT * 4;

// ---------------------------------------------------------------------------
// K1: transpose + pack y:  y[b][k][n] (int32, 0..255)  ->  yt[b][n][k] (int8, y-128)
// plus per-(k-tile, b, n) partial colsums of y' into csp.
// 64x64 tiles through LDS. Grid: (N/64, K/64, B), block 256.
// ---------------------------------------------------------------------------
__global__ __launch_bounds__(256) void transpose_pack_y(const int* __restrict__ y,
                                                        signed char* __restrict__ yt,
                                                        int* __restrict__ csp) {
    __shared__ unsigned char tile[64][80];       // 80 = 5*16: 16B-aligned rows, odd 16-bank phase
    int n0  = blockIdx.x * 64;
    int k0t = blockIdx.y;
    int k0  = k0t * 64;
    int b   = blockIdx.z;
    int t   = threadIdx.x;

    // phase 1: coalesced read along n, pack low bytes (^0x80 == y-128 as i8), 16B to LDS
    int r  = t >> 2;                              // k-local 0..63
    int c0 = (t & 3) * 16;                        // n-local byte offset
    const int* src = y + ((size_t)b * K + k0 + r) * N + n0 + c0;
    uint32_t p[4];
#pragma unroll
    for (int q = 0; q < 4; ++q) {
        int4 v = ((const int4*)src)[q];
        p[q] =  (uint32_t)((v.x & 255) ^ 128)
             | ((uint32_t)((v.y & 255) ^ 128) << 8)
             | ((uint32_t)((v.z & 255) ^ 128) << 16)
             | ((uint32_t)((v.w & 255) ^ 128) << 24);
    }
    *(uint4*)&tile[r][c0] = make_uint4(p[0], p[1], p[2], p[3]);
    __syncthreads();

    // phase 2: gather a column of 16 k-bytes per thread, write 16B contiguous in k
    int nl = t >> 2;                              // n-local 0..63
    int kc = (t & 3) * 16;                        // k-local byte offset
    uint32_t q[4];
    int s = 0;
#pragma unroll
    for (int w = 0; w < 4; ++w) {
        uint32_t b0 = tile[kc + w * 4 + 0][nl];
        uint32_t b1 = tile[kc + w * 4 + 1][nl];
        uint32_t b2 = tile[kc + w * 4 + 2][nl];
        uint32_t b3 = tile[kc + w * 4 + 3][nl];
        s += (int)(signed char)b0 + (int)(signed char)b1
           + (int)(signed char)b2 + (int)(signed char)b3;
        q[w] = b0 | (b1 << 8) | (b2 << 16) | (b3 << 24);
    }
    *(uint4*)(yt + ((size_t)b * N + n0 + nl) * K + k0 + kc) = make_uint4(q[0], q[1], q[2], q[3]);

    // quad-reduce partial colsum (4 threads cover 64 k for one n)
    s += __shfl_xor(s, 1, 64);
    s += __shfl_xor(s, 2, 64);
    if ((t & 3) == 0) csp[(size_t)k0t * (B * N) + b * N + n0 + nl] = s;
}

// ---------------------------------------------------------------------------
// K2 (fused GEMM): EXACTLY the round-1 structure (measured 69.6us, the session
// best) + K-PHASE STAGGER. Block = 128m x 512n (full N) for one (gb, mt).
// 512 threads, 8 waves (2m x 4n), each wave 64x128 via 4x8 tiles of
// mfma_i32_16x16x64_i8. 2 waves/SIMD -> 256 unified regs (VGPR 128 + AGPR 128)
// -- the budget round-5 proved necessary for the compiler to pipeline.
//
// STAGGER (the one change): block processes k-tiles in order (t + phi) & 15,
// phi = swz & 15. Round-1 counters showed per-step staged-A bursts served at
// ~1.65 TB/s effective: all 224 blocks read the SAME 256B-per-4KB-page k-slice
// of x simultaneously (channel concentration + synchronized queueing tail at
// each barrier). Staggering spreads the fleet across 16 k-slices -> all HBM
// channels covered at any instant. Integer accumulation -> bit-identical.
//
// A read from x (int32) ONCE, packed in-register -> swizzled ds_write;
// rowsums accumulate inline. B staged via global_load_lds from yt (pre-
// swizzled source). Double-buffered LDS, ONE __syncthreads per K-step
// (standard drain semantics — no exotic sync). Prefetch t+1 issued AFTER the
// barrier (av first, then B, so pack's vmcnt wait retires only av).
// LDS swizzle: physical 16B slot p in each 64B row holds k-chunk p^((row>>1)&3)
// (readers use fk = ((lane>>4) ^ ((fr>>1)&3))*16) -> 2-way bank alias = free.
// Grid: 224 blocks = 56 gb x 4 mt, XCD-bijective swizzle.
// ---------------------------------------------------------------------------
__global__ __launch_bounds__(512, 2) void gemm_fused(const int* __restrict__ x,
                                                     const signed char* __restrict__ yt,
                                                     const int* __restrict__ csp,
                                                     const float* __restrict__ xsp,
                                                     const float* __restrict__ ysp,
                                                     float* __restrict__ out) {
    __shared__ __align__(16) signed char As[2][128 * 64];   // 16 KiB
    __shared__ __align__(16) signed char Bs[2][512 * 64];   // 64 KiB
    __shared__ int cs_lds[512];
    __shared__ int rs_lds[128];

    int id  = blockIdx.x;                         // 0..223
    int swz = (id & 7) * 28 + (id >> 3);          // XCD-contiguous chunks (224%8==0, bijective)
    int gb  = swz >> 2;                           // 0..55
    int mt  = swz & 3;                            // 0..3
    int b   = gb & 7;
    int phi = swz & 15;                           // k-phase stagger

    int tid = threadIdx.x, wave = tid >> 6, lane = tid & 63;

    // block colsums: each thread sums 16 per-k-tile partials for one n
    {
        int s = 0;
        const int* p = csp + b * N + tid;
#pragma unroll
        for (int kt = 0; kt < 16; ++kt) s += p[(size_t)kt * (B * N)];
        cs_lds[tid] = s;
    }

    // A staging: thread t handles row t>>2 (0..127), k-quad t&3 (16 ints)
    int arow = tid >> 2;
    int akq  = tid & 3;
    const int4* Asrc = (const int4*)(x + ((size_t)(gb * M + mt * 128 + arow)) * K) + akq * 4;
    int aoff = arow * 64 + ((akq ^ ((arow >> 1) & 3)) << 4);   // swizzled ds_write addr

    // B staging: per wave, call c stages rows c*128 + wave*16 + (lane>>2)
    int brl    = lane >> 2;
    int bchunk = (lane & 3) ^ ((lane >> 3) & 3);               // pre-swizzled source chunk
    const signed char* Bsrc = yt + ((size_t)b * N) * K;

    // fragment read offsets
    int fr = lane & 15;
    int fk = ((lane >> 4) ^ ((fr >> 1) & 3)) << 4;
    int wm = (wave >> 2) * 64;                    // 0 or 64
    int wn = (wave & 3) * 128;                    // 0,128,256,384

    v4i zero = {0, 0, 0, 0};
    v4i acc[4][8];
#pragma unroll
    for (int i = 0; i < 4; ++i)
#pragma unroll
        for (int j = 0; j < 8; ++j) acc[i][j] = zero;

    int rsum = 0;

    // prologue: A(phi) -> regs (issued first), B(phi) -> Bs[0]
    int4 av[4];
#pragma unroll
    for (int q = 0; q < 4; ++q) av[q] = Asrc[phi * 16 + q];
#pragma unroll
    for (int c = 0; c < 4; ++c) {
        __builtin_amdgcn_global_load_lds(
            (const AS1 uint32_t*)(Bsrc + (size_t)(c * 128 + wave * 16 + brl) * K
                                  + phi * 64 + bchunk * 16),
            (AS3 uint32_t*)(&Bs[0][(c * 128 + wave * 16) * 64]), 16, 0, 0);
    }

#pragma unroll 2
    for (int t = 0; t < 16; ++t) {
        int cur = t & 1;
        int kt  = (t + phi) & 15;                  // this step's k-tile

        // pack A(t) -> LDS, accumulate rowsum (vmcnt waits only for av)
        uint32_t pw[4];
        int s = 0;
#pragma unroll
        for (int q = 0; q < 4; ++q) {
            int4 v = av[q];
            s += v.x + v.y + v.z + v.w;
            pw[q] =  (uint32_t)(v.x & 255)
                 | ((uint32_t)(v.y & 255) << 8)
                 | ((uint32_t)(v.z & 255) << 16)
                 | ((uint32_t)(v.w & 255) << 24);
        }
        rsum += s;
        *(uint4*)(&As[cur][aoff]) = make_uint4(pw[0], pw[1], pw[2], pw[3]);

        __syncthreads();   // drains B(t) gloads + A(t) ds_writes: buf[cur] ready

        // issue next step's loads (av first, then B): they fly under
        // ds_reads + MFMAs and are drained by the NEXT barrier.
        if (t < 15) {
            int ktn = (kt + 1) & 15;
#pragma unroll
            for (int q = 0; q < 4; ++q) av[q] = Asrc[ktn * 16 + q];
#pragma unroll
            for (int c = 0; c < 4; ++c) {
                __builtin_amdgcn_global_load_lds(
                    (const AS1 uint32_t*)(Bsrc + (size_t)(c * 128 + wave * 16 + brl) * K
                                          + ktn * 64 + bchunk * 16),
                    (AS3 uint32_t*)(&Bs[cur ^ 1][(c * 128 + wave * 16) * 64]), 16, 0, 0);
            }
        }

        v4i af[4], bf[8];
#pragma unroll
        for (int i = 0; i < 4; ++i)
            af[i] = *(const v4i*)(&As[cur][(wm + i * 16 + fr) * 64 + fk]);
#pragma unroll
        for (int j = 0; j < 8; ++j)
            bf[j] = *(const v4i*)(&Bs[cur][(wn + j * 16 + fr) * 64 + fk]);

#pragma unroll
        for (int i = 0; i < 4; ++i)
#pragma unroll
            for (int j = 0; j < 8; ++j)
                acc[i][j] = __builtin_amdgcn_mfma_i32_16x16x64_i8(af[i], bf[j], acc[i][j], 0, 0, 0);
        // no second barrier: next step writes the OTHER buffer; the single
        // block-wide barrier above orders read(t-1) < write(t+1).
    }

    // rowsum: quad-reduce (4 threads per row), publish to LDS
    rsum += __shfl_xor(rsum, 1, 64);
    rsum += __shfl_xor(rsum, 2, 64);
    if ((tid & 3) == 0) rs_lds[arow] = rsum;
    __syncthreads();

    // epilogue: C = s * (dot - 32*rowsum_x + 66*colsum_y' - 2162688)
    float sc = xsp[0] * ysp[0];
    int colL = lane & 15;
    int rowQ = (lane >> 4) * 4;
    float* outg = out + (size_t)gb * (M * N) + (size_t)(mt * 128) * N;
#pragma unroll
    for (int i = 0; i < 4; ++i) {
#pragma unroll
        for (int r = 0; r < 4; ++r) {
            int row_l = wm + i * 16 + rowQ + r;
            int rsv = rs_lds[row_l];
#pragma unroll
            for (int j = 0; j < 8; ++j) {
                int col = wn + j * 16 + colL;
                int tv = acc[i][j][r] - 32 * rsv + 66 * cs_lds[col] - 2162688;
                outg[(size_t)row_l * N + col] = sc * (float)tv;
            }
        }
    }
}

// ---------------------------------------------------------------------------
// Fallback (only if ws_size is too small): naive but correct.
// sum (x-X)(y-Y) = dot(x,y) - 160*sum_x + 66*sum_y - 10,813,440
// ---------------------------------------------------------------------------
__global__ __launch_bounds__(256) void naive_kernel(const int* __restrict__ x,
                                                    const int* __restrict__ y,
                                                    const float* __restrict__ xsp,
                                                    const float* __restrict__ ysp,
                                                    float* __restrict__ out) {
    size_t idx = (size_t)blockIdx.x * 256 + threadIdx.x;   // over 14,680,064
    int n  = (int)(idx & 511);
    int m  = (int)((idx >> 9) & 511);
    int gb = (int)(idx >> 18);
    int b  = gb & 7;
    const int* xr = x + ((size_t)gb * M + m) * K;
    const int* yc = y + (size_t)b * K * N + n;
    int dot = 0, sx = 0, sy = 0;
    for (int k = 0; k < K; ++k) {
        int a = xr[k];
        int c = yc[(size_t)k * N];
        dot += a * c; sx += a; sy += c;
    }
    float s = xsp[0] * ysp[0];
    out[idx] = s * (float)(dot - 160 * sx + 66 * sy - 10813440);
}

// ---------------------------------------------------------------------------
extern "C" void kernel_launch(void* const* d_in, const int* in_sizes, int n_in,
                              void* d_out, int out_size, void* d_ws, size_t ws_size,
                              hipStream_t stream) {
    const int*   x  = (const int*)d_in[0];     // [7,8,512,1024] int8 values in int32
    const int*   y  = (const int*)d_in[1];     // [8,1024,512] uint8 values in int32
    const float* xs = (const float*)d_in[2];
    const float* ys = (const float*)d_in[3];
    float* out = (float*)d_out;

    if (ws_size < WS_NEEDED) {
        naive_kernel<<<(14680064 + 255) / 256, 256, 0, stream>>>(x, y, xs, ys, out);
        return;
    }

    char* ws = (char*)d_ws;
    signed char* yt  = (signed char*)ws;
    int*         csp = (int*)(ws + YT_BYTES);

    transpose_pack_y<<<dim3(N / 64, K / 64, B), 256, 0, stream>>>(y, yt, csp);
    gemm_fused<<<dim3(224), 512, 0, stream>>>(x, yt, csp, xs, ys, out);
}